// Round 7
// baseline (1036.495 us; speedup 1.0000x reference)
//
#include <hip/hip_runtime.h>

#define L 512
#define D 128
#define H 4
#define HD 32
#define XLD 132   // padded LDS leading dim (floats)
#define NBLK 512  // persistent grid: 2 blocks/CU guaranteed resident

typedef __bf16 bf16x8 __attribute__((ext_vector_type(8)));
typedef float  f32x4  __attribute__((ext_vector_type(4)));

__device__ __forceinline__ unsigned short bfbits(float v){
  __bf16 h = (__bf16)v; unsigned short u; __builtin_memcpy(&u, &h, 2); return u;
}
__device__ __forceinline__ bf16x8 cvt8(float4 a0, float4 a1){
  bf16x8 r;
  r[0] = (__bf16)a0.x; r[1] = (__bf16)a0.y; r[2] = (__bf16)a0.z; r[3] = (__bf16)a0.w;
  r[4] = (__bf16)a1.x; r[5] = (__bf16)a1.y; r[6] = (__bf16)a1.z; r[7] = (__bf16)a1.w;
  return r;
}

// ---------------- device-scope grid barrier (all NBLK blocks resident) ------
__device__ __forceinline__ void gridbar(unsigned* cnt, unsigned* gen){
  __threadfence();                       // release: drain + L2 writeback (cross-XCD)
  __syncthreads();
  if (threadIdx.x == 0){
    unsigned g = __hip_atomic_load(gen, __ATOMIC_RELAXED, __HIP_MEMORY_SCOPE_AGENT);
    unsigned arr = __hip_atomic_fetch_add(cnt, 1u, __ATOMIC_ACQ_REL, __HIP_MEMORY_SCOPE_AGENT);
    if (arr == NBLK - 1u){
      __hip_atomic_store(cnt, 0u, __ATOMIC_RELAXED, __HIP_MEMORY_SCOPE_AGENT);
      __hip_atomic_fetch_add(gen, 1u, __ATOMIC_ACQ_REL, __HIP_MEMORY_SCOPE_AGENT);
    } else {
      unsigned t = 0;
      while (__hip_atomic_load(gen, __ATOMIC_ACQUIRE, __HIP_MEMORY_SCOPE_AGENT) == g){
        __builtin_amdgcn_s_sleep(2);
        if (++t > (1u << 28)) break;     // bounded: fail visibly, never hang
      }
    }
  }
  __syncthreads();
  __threadfence();                       // acquire: invalidate L1/L2-stale lines
}

// -------- fragment-write helpers (thread owns value at (row, c)) ------------
__device__ __forceinline__ void write_qA(unsigned short* qA, int row, int c, float v){
  int qt = row >> 4, m = row & 15;
  int h = c >> 5, cc = c & 31;
  qA[(((qt * 4 + h) * 64) + (cc >> 3) * 16 + m) * 8 + (cc & 7)] = bfbits(v);
}
__device__ __forceinline__ void write_kB(unsigned short* kB, int row, int c, float v){
  int h = c >> 5, cc = c & 31;
  int nt = row >> 4;
  kB[((h * 32 + nt) * 64 + (cc >> 3) * 16 + (row & 15)) * 8 + (cc & 7)] = bfbits(v);
}
__device__ __forceinline__ void write_vB(unsigned short* vB, int row, int c, float v){
  int h = c >> 5, cc = c & 31;
  int kk = row >> 5, qv = (row >> 3) & 3, jv = row & 7;
  int nt = cc >> 4;
  vB[(((h * 16 + kk) * 2 + nt) * 64 + qv * 16 + (cc & 15)) * 8 + jv] = bfbits(v);
}

// ---- per-16-row stats -------------------------------------------------------
__device__ __forceinline__ void row_stats16(const float (*buf)[XLD], int tid,
                                            float* mean_s, float* rstd_s){
  int row_l = tid >> 4, seg = tid & 15;
  const float* p = &buf[row_l][seg * 8];
  float4 f0 = *(const float4*)p, f1 = *(const float4*)(p + 4);
  float sum = f0.x + f0.y + f0.z + f0.w + f1.x + f1.y + f1.z + f1.w;
  float sq  = f0.x*f0.x + f0.y*f0.y + f0.z*f0.z + f0.w*f0.w
            + f1.x*f1.x + f1.y*f1.y + f1.z*f1.z + f1.w*f1.w;
#pragma unroll
  for (int o = 1; o < 16; o <<= 1){ sum += __shfl_xor(sum, o); sq += __shfl_xor(sq, o); }
  if (seg == 0){
    float mn = sum * (1.f / 128.f);
    mean_s[row_l] = mn;
    rstd_s[row_l] = rsqrtf(fmaxf(sq * (1.f / 128.f) - mn * mn, 0.f) + 1e-8f);
  }
}

// ---- A-fragment builders from a 16x128 LDS tile ----------------------------
__device__ __forceinline__ void build_afr(const float (*buf)[XLD], int lane, bf16x8* afr){
  int m = lane & 15, quad = lane >> 4;
#pragma unroll
  for (int k0 = 0; k0 < 4; ++k0){
    const float* p = &buf[m][k0 * 32 + quad * 8];
    afr[k0] = cvt8(*(const float4*)p, *(const float4*)(p + 4));
  }
}
__device__ __forceinline__ void build_afr_ln(const float (*buf)[XLD], int lane,
    const float* mean_s, const float* rstd_s,
    const float* __restrict__ g, const float* __restrict__ b, bf16x8* afr){
  int m = lane & 15, quad = lane >> 4;
  float mn = mean_s[m], rs = rstd_s[m];
#pragma unroll
  for (int k0 = 0; k0 < 4; ++k0){
    int c0 = k0 * 32 + quad * 8;
    const float* p = &buf[m][c0];
    float4 a0 = *(const float4*)p, a1 = *(const float4*)(p + 4);
    float q[8];
    q[0]=(a0.x-mn)*rs*g[c0+0]+b[c0+0]; q[1]=(a0.y-mn)*rs*g[c0+1]+b[c0+1];
    q[2]=(a0.z-mn)*rs*g[c0+2]+b[c0+2]; q[3]=(a0.w-mn)*rs*g[c0+3]+b[c0+3];
    q[4]=(a1.x-mn)*rs*g[c0+4]+b[c0+4]; q[5]=(a1.y-mn)*rs*g[c0+5]+b[c0+5];
    q[6]=(a1.z-mn)*rs*g[c0+6]+b[c0+6]; q[7]=(a1.w-mn)*rs*g[c0+7]+b[c0+7];
    bf16x8 r;
    r[0]=(__bf16)q[0]; r[1]=(__bf16)q[1]; r[2]=(__bf16)q[2]; r[3]=(__bf16)q[3];
    r[4]=(__bf16)q[4]; r[5]=(__bf16)q[5]; r[6]=(__bf16)q[6]; r[7]=(__bf16)q[7];
    afr[k0] = r;
  }
}

// ---------------- phase: LN1 + QKV for a 16-row tile of one matrix ----------
__device__ void qkv_part(int unit, const float* __restrict__ src,
    const int* __restrict__ ls,
    const float* __restrict__ g1, const float* __restrict__ b1,
    const unsigned short* __restrict__ wf,
    const float* __restrict__ bq, const float* __restrict__ bk,
    const float* __restrict__ bv,
    float* __restrict__ Q, unsigned short* __restrict__ qA,
    unsigned short* __restrict__ kB, unsigned short* __restrict__ vB,
    unsigned char* smem){
  float (*xs)[XLD] = (float(*)[XLD])smem;
  float* mean_s = (float*)(smem + 8448);
  float* rstd_s = mean_s + 16;
  float* g1s = (float*)(smem + 8576);
  float* b1s = g1s + 128;
  int tid = threadIdx.x;
  int rowbase = (unit & 31) * 16;
  int mat = unit >> 5;                           // 0=q,1=k,2=v
  int row_l = tid >> 4, seg = tid & 15;
  int lane = tid & 63, w = tid >> 6;
  int quad = lane >> 4, mcol = lane & 15;

  __syncthreads();                               // smem may be in use (tb phase)
  const float* sp = src + (rowbase + row_l) * D + seg * 8;
  float4 f0 = *(const float4*)sp, f1 = *(const float4*)(sp + 4);
  if (ls[rowbase + row_l] == 0){
    f0 = make_float4(0,0,0,0); f1 = make_float4(0,0,0,0);
  }
  *(float4*)&xs[row_l][seg * 8] = f0;
  *(float4*)&xs[row_l][seg * 8 + 4] = f1;
  if (mat == 0 && tid < 128){ g1s[tid] = g1[tid]; b1s[tid] = b1[tid]; }
  __syncthreads();
  if (mat == 0){
    row_stats16(xs, tid, mean_s, rstd_s);
    __syncthreads();
    float mn = mean_s[row_l], rs = rstd_s[row_l];
    float* qp = Q + (rowbase + row_l) * D + seg * 8;
    float4 o0, o1;
    int c0 = seg * 8;
    o0.x=(f0.x-mn)*rs*g1s[c0+0]+b1s[c0+0]; o0.y=(f0.y-mn)*rs*g1s[c0+1]+b1s[c0+1];
    o0.z=(f0.z-mn)*rs*g1s[c0+2]+b1s[c0+2]; o0.w=(f0.w-mn)*rs*g1s[c0+3]+b1s[c0+3];
    o1.x=(f1.x-mn)*rs*g1s[c0+4]+b1s[c0+4]; o1.y=(f1.y-mn)*rs*g1s[c0+5]+b1s[c0+5];
    o1.z=(f1.z-mn)*rs*g1s[c0+6]+b1s[c0+6]; o1.w=(f1.w-mn)*rs*g1s[c0+7]+b1s[c0+7];
    *(float4*)qp = o0; *(float4*)(qp + 4) = o1;
  }

  bf16x8 afr[4];
  if (mat == 0) build_afr_ln(xs, lane, mean_s, rstd_s, g1s, b1s, afr);
  else          build_afr(xs, lane, afr);

  const float* bias_v = (mat == 0 ? bq : mat == 1 ? bk : bv);
#pragma unroll
  for (int jl = 0; jl < 2; ++jl){
    int nt = w * 2 + jl;
    const bf16x8* wfb = (const bf16x8*)wf + ((size_t)mat * 8 + nt) * 4 * 64;
    f32x4 acc = {0, 0, 0, 0};
#pragma unroll
    for (int k0 = 0; k0 < 4; ++k0)
      acc = __builtin_amdgcn_mfma_f32_16x16x32_bf16(afr[k0], wfb[k0 * 64 + lane], acc, 0, 0, 0);
    int c = nt * 16 + mcol;
    float bias = bias_v[c];
#pragma unroll
    for (int r = 0; r < 4; ++r){
      int row = rowbase + quad * 4 + r;
      float v = acc[r] + bias;
      if (mat == 0) write_qA(qA, row, c, v);
      else if (mat == 1) write_kB(kB, row, c, v);
      else write_vB(vB, row, c, v);
    }
  }
}

// ---------------- phase: MFMA attention for one (qtile, head) ---------------
__device__ void attn_part(int unit,
    const unsigned short* __restrict__ qA, const unsigned short* __restrict__ kB,
    const unsigned short* __restrict__ vB, const float* __restrict__ logtw,
    const int* __restrict__ ls, const float* __restrict__ Q,
    float* __restrict__ wout, float* __restrict__ xr, unsigned char* smem){
  unsigned short* pa = (unsigned short*)smem;                 // 16 KB
  float (*pvp)[2][64][4] = (float(*)[2][64][4])(smem + 16384); // 8 KB
  float (*smax)[16] = (float(*)[16])(smem + 24576);
  float (*ssum)[16] = (float(*)[16])(smem + 24832);
  int qt = unit >> 2, h = unit & 3;
  int tid = threadIdx.x, lane = tid & 63, w = tid >> 6;
  int quad = lane >> 4, mcol = lane & 15;
  const float RS = 0.17677669529663687f;
  int row_max = qt * 16 + 15;
  bool skipw = (w * 128) > row_max;

  float e[8][4];
  if (!skipw){
    bf16x8 qf = ((const bf16x8*)qA)[(qt * 4 + h) * 64 + lane];
    f32x4 acc[8];
#pragma unroll
    for (int nt8 = 0; nt8 < 8; ++nt8){
      bf16x8 bf = ((const bf16x8*)kB)[(h * 32 + w * 8 + nt8) * 64 + lane];
      f32x4 z = {0, 0, 0, 0};
      acc[nt8] = __builtin_amdgcn_mfma_f32_16x16x32_bf16(qf, bf, z, 0, 0, 0);
    }
#pragma unroll
    for (int nt8 = 0; nt8 < 8; ++nt8){
      int col = w * 128 + nt8 * 16 + mcol;
#pragma unroll
      for (int r = 0; r < 4; ++r){
        int row = qt * 16 + quad * 4 + r;
        float sv = (acc[nt8][r] + logtw[row * L + col]) * RS;
        e[nt8][r] = (col <= row) ? sv : -3e38f;
      }
    }
  } else {
#pragma unroll
    for (int nt8 = 0; nt8 < 8; ++nt8)
#pragma unroll
      for (int r = 0; r < 4; ++r) e[nt8][r] = -3e38f;
  }

  float mx4[4] = {-3e38f, -3e38f, -3e38f, -3e38f};
#pragma unroll
  for (int nt8 = 0; nt8 < 8; ++nt8)
#pragma unroll
    for (int r = 0; r < 4; ++r) mx4[r] = fmaxf(mx4[r], e[nt8][r]);
#pragma unroll
  for (int r = 0; r < 4; ++r){
    float v = mx4[r];
    v = fmaxf(v, __shfl_xor(v, 1)); v = fmaxf(v, __shfl_xor(v, 2));
    v = fmaxf(v, __shfl_xor(v, 4)); v = fmaxf(v, __shfl_xor(v, 8));
    mx4[r] = v;
  }
  if (mcol == 0){
#pragma unroll
    for (int r = 0; r < 4; ++r) smax[w][quad * 4 + r] = mx4[r];
  }
  __syncthreads();
  float mxr[4], sum4[4] = {0, 0, 0, 0};
#pragma unroll
  for (int r = 0; r < 4; ++r){
    int rr = quad * 4 + r;
    mxr[r] = fmaxf(fmaxf(smax[0][rr], smax[1][rr]), fmaxf(smax[2][rr], smax[3][rr]));
  }
#pragma unroll
  for (int nt8 = 0; nt8 < 8; ++nt8)
#pragma unroll
    for (int r = 0; r < 4; ++r){
      float sv = e[nt8][r];
      float ev = (sv > -1e38f) ? __expf(sv - mxr[r]) : 0.f;
      e[nt8][r] = ev;
      sum4[r] += ev;
    }
#pragma unroll
  for (int r = 0; r < 4; ++r){
    float v = sum4[r];
    v += __shfl_xor(v, 1); v += __shfl_xor(v, 2);
    v += __shfl_xor(v, 4); v += __shfl_xor(v, 8);
    sum4[r] = v;
  }
  if (mcol == 0){
#pragma unroll
    for (int r = 0; r < 4; ++r) ssum[w][quad * 4 + r] = sum4[r];
  }
  __syncthreads();
  float inv[4]; int padr[4];
#pragma unroll
  for (int r = 0; r < 4; ++r){
    int rr = quad * 4 + r;
    inv[r] = 1.f / (ssum[0][rr] + ssum[1][rr] + ssum[2][rr] + ssum[3][rr]);
    padr[r] = (ls[qt * 16 + rr] == 0);
  }
#pragma unroll
  for (int nt8 = 0; nt8 < 8; ++nt8){
    int col = w * 128 + nt8 * 16 + mcol;
    int kk = col >> 5, qk = (col >> 3) & 3, jj = col & 7;
#pragma unroll
    for (int r = 0; r < 4; ++r){
      int rl = quad * 4 + r;
      float wv = padr[r] ? (1.f / 512.f) : e[nt8][r] * inv[r];
      wout[h * (L * L) + (qt * 16 + rl) * L + col] = wv;
      if (!skipw) pa[(kk * 64 + qk * 16 + rl) * 8 + jj] = bfbits(wv);
    }
  }

  f32x4 pacc[2] = {{0,0,0,0},{0,0,0,0}};
  if (!skipw){
#pragma unroll
    for (int kk4 = 0; kk4 < 4; ++kk4){
      int kk = w * 4 + kk4;
      bf16x8 af = ((const bf16x8*)pa)[kk * 64 + lane];
#pragma unroll
      for (int nt = 0; nt < 2; ++nt){
        bf16x8 bf = ((const bf16x8*)vB)[((h * 16 + kk) * 2 + nt) * 64 + lane];
        pacc[nt] = __builtin_amdgcn_mfma_f32_16x16x32_bf16(af, bf, pacc[nt], 0, 0, 0);
      }
    }
  }
#pragma unroll
  for (int nt = 0; nt < 2; ++nt)
#pragma unroll
    for (int r = 0; r < 4; ++r) pvp[w][nt][lane][r] = pacc[nt][r];
  __syncthreads();
  if (w < 2){
    int nt = w;
#pragma unroll
    for (int r = 0; r < 4; ++r){
      float o = pvp[0][nt][lane][r] + pvp[1][nt][lane][r]
              + pvp[2][nt][lane][r] + pvp[3][nt][lane][r];
      int row = qt * 16 + quad * 4 + r;
      int cg = h * HD + nt * 16 + mcol;
      xr[row * D + cg] = Q[row * D + cg] + o;
    }
  }
}

// ------- phase: LN2+FFN (+keep); optional fused LN1+QKV next / final LN -----
__device__ void ffn_part(int unit, const float* __restrict__ xr,
    const int* __restrict__ ls,
    const float* __restrict__ g2, const float* __restrict__ b2,
    const unsigned short* __restrict__ wf, int mat1,
    const float* __restrict__ b1f, const float* __restrict__ b2f,
    int fuse_qkv, const float* __restrict__ g1, const float* __restrict__ b1,
    int matq, const float* __restrict__ bq, const float* __restrict__ bk,
    const float* __restrict__ bv,
    float* __restrict__ Q, unsigned short* __restrict__ qA,
    unsigned short* __restrict__ kB, unsigned short* __restrict__ vB,
    int fuse_lnf, const float* __restrict__ lg, const float* __restrict__ lb,
    float* __restrict__ lf, unsigned char* smem){
  float (*xs)[XLD]  = (float(*)[XLD])smem;
  float (*x2s)[XLD] = (float(*)[XLD])(smem + 8448);
  float (*y1s)[XLD] = (float(*)[XLD])(smem + 16896);
  float (*xos)[XLD] = (float(*)[XLD])(smem + 25344);
  float* mean_s = (float*)(smem + 33792);
  float* rstd_s = mean_s + 16;
  float* gs = (float*)(smem + 33920);
  float* bs = gs + 128;
  int tid = threadIdx.x, rowbase = unit * 16;
  int row_l = tid >> 4, seg = tid & 15;
  int lane = tid & 63, w = tid >> 6;
  int quad = lane >> 4, mcol = lane & 15;

  {
    const float* sp = xr + (rowbase + row_l) * D + seg * 8;
    *(float4*)&xs[row_l][seg * 8] = *(const float4*)sp;
    *(float4*)&xs[row_l][seg * 8 + 4] = *(const float4*)(sp + 4);
    if (tid < 128){ gs[tid] = g2[tid]; bs[tid] = b2[tid]; }
  }
  __syncthreads();
  row_stats16(xs, tid, mean_s, rstd_s);
  __syncthreads();
  {
    float mn = mean_s[row_l], rs = rstd_s[row_l];
#pragma unroll
    for (int i = 0; i < 8; ++i){
      int c = seg * 8 + i;
      x2s[row_l][c] = (xs[row_l][c] - mn) * rs * gs[c] + bs[c];
    }
  }
  __syncthreads();

  bf16x8 afr[4];
  build_afr(x2s, lane, afr);
#pragma unroll
  for (int jl = 0; jl < 2; ++jl){
    int nt = w * 2 + jl;
    const bf16x8* wfb = (const bf16x8*)wf + ((size_t)mat1 * 8 + nt) * 4 * 64;
    f32x4 acc = {0, 0, 0, 0};
#pragma unroll
    for (int k0 = 0; k0 < 4; ++k0)
      acc = __builtin_amdgcn_mfma_f32_16x16x32_bf16(afr[k0], wfb[k0 * 64 + lane], acc, 0, 0, 0);
    int c = nt * 16 + mcol;
    float bias = b1f[c];
#pragma unroll
    for (int r = 0; r < 4; ++r)
      y1s[quad * 4 + r][c] = fmaxf(acc[r] + bias, 0.f);
  }
  __syncthreads();

  build_afr(y1s, lane, afr);
#pragma unroll
  for (int jl = 0; jl < 2; ++jl){
    int nt = w * 2 + jl;
    const bf16x8* wfb = (const bf16x8*)wf + ((size_t)(mat1 + 1) * 8 + nt) * 4 * 64;
    f32x4 acc = {0, 0, 0, 0};
#pragma unroll
    for (int k0 = 0; k0 < 4; ++k0)
      acc = __builtin_amdgcn_mfma_f32_16x16x32_bf16(afr[k0], wfb[k0 * 64 + lane], acc, 0, 0, 0);
    int c = nt * 16 + mcol;
    float bias = b2f[c];
#pragma unroll
    for (int r = 0; r < 4; ++r){
      int rl = quad * 4 + r;
      float kp = (ls[rowbase + rl] != 0) ? 1.f : 0.f;
      xos[rl][c] = (x2s[rl][c] + acc[r] + bias) * kp;
    }
  }
  __syncthreads();

  if (fuse_qkv){
    if (tid < 128){ gs[tid] = g1[tid]; bs[tid] = b1[tid]; }
    row_stats16(xos, tid, mean_s, rstd_s);
    __syncthreads();
    {
      float mn = mean_s[row_l], rs = rstd_s[row_l];
      float* qp = Q + (rowbase + row_l) * D + seg * 8;
      float4 o0, o1;
      int c0 = seg * 8;
      o0.x=(xos[row_l][c0+0]-mn)*rs*gs[c0+0]+bs[c0+0];
      o0.y=(xos[row_l][c0+1]-mn)*rs*gs[c0+1]+bs[c0+1];
      o0.z=(xos[row_l][c0+2]-mn)*rs*gs[c0+2]+bs[c0+2];
      o0.w=(xos[row_l][c0+3]-mn)*rs*gs[c0+3]+bs[c0+3];
      o1.x=(xos[row_l][c0+4]-mn)*rs*gs[c0+4]+bs[c0+4];
      o1.y=(xos[row_l][c0+5]-mn)*rs*gs[c0+5]+bs[c0+5];
      o1.z=(xos[row_l][c0+6]-mn)*rs*gs[c0+6]+bs[c0+6];
      o1.w=(xos[row_l][c0+7]-mn)*rs*gs[c0+7]+bs[c0+7];
      *(float4*)qp = o0; *(float4*)(qp + 4) = o1;
    }
    bf16x8 afrQ[4], afrX[4];
    build_afr_ln(xos, lane, mean_s, rstd_s, gs, bs, afrQ);
    build_afr(xos, lane, afrX);
#pragma unroll
    for (int jl = 0; jl < 6; ++jl){
      int j = w * 6 + jl;
      int mat = j >> 3, nt = j & 7;
      const bf16x8* wfb = (const bf16x8*)wf + ((size_t)(matq + mat) * 8 + nt) * 4 * 64;
      f32x4 acc = {0, 0, 0, 0};
#pragma unroll
      for (int k0 = 0; k0 < 4; ++k0)
        acc = __builtin_amdgcn_mfma_f32_16x16x32_bf16(mat == 0 ? afrQ[k0] : afrX[k0],
                                                      wfb[k0 * 64 + lane], acc, 0, 0, 0);
      int c = nt * 16 + mcol;
      float bias = (mat == 0 ? bq : mat == 1 ? bk : bv)[c];
#pragma unroll
      for (int r = 0; r < 4; ++r){
        int row = rowbase + quad * 4 + r;
        float v = acc[r] + bias;
        if (mat == 0) write_qA(qA, row, c, v);
        else if (mat == 1) write_kB(kB, row, c, v);
        else write_vB(vB, row, c, v);
      }
    }
  }

  if (fuse_lnf){
    if (tid < 128){ gs[tid] = lg[tid]; bs[tid] = lb[tid]; }
    row_stats16(xos, tid, mean_s, rstd_s);
    __syncthreads();
    float mn = mean_s[row_l], rs = rstd_s[row_l];
    float* op = lf + (rowbase + row_l) * D + seg * 8;
    float4 o0, o1;
    int c0 = seg * 8;
    o0.x=(xos[row_l][c0+0]-mn)*rs*gs[c0+0]+bs[c0+0];
    o0.y=(xos[row_l][c0+1]-mn)*rs*gs[c0+1]+bs[c0+1];
    o0.z=(xos[row_l][c0+2]-mn)*rs*gs[c0+2]+bs[c0+2];
    o0.w=(xos[row_l][c0+3]-mn)*rs*gs[c0+3]+bs[c0+3];
    o1.x=(xos[row_l][c0+4]-mn)*rs*gs[c0+4]+bs[c0+4];
    o1.y=(xos[row_l][c0+5]-mn)*rs*gs[c0+5]+bs[c0+5];
    o1.z=(xos[row_l][c0+6]-mn)*rs*gs[c0+6]+bs[c0+6];
    o1.w=(xos[row_l][c0+7]-mn)*rs*gs[c0+7]+bs[c0+7];
    *(float4*)op = o0; *(float4*)(op + 4) = o1;
  }
}

// =============== persistent mega-kernel: all phases, 5 grid barriers ========
__global__ __launch_bounds__(256, 2) void k_mega(
    const float* __restrict__ T, const int* __restrict__ ls,
    const float* __restrict__ seqs,
    const float* __restrict__ Wt, const float* __restrict__ Wq,
    const float* __restrict__ Wk, const float* __restrict__ Wv,
    const float* __restrict__ W1, const float* __restrict__ W2,
    const float* __restrict__ bt, const float* __restrict__ wtp,
    const float* __restrict__ btp,
    const float* __restrict__ g1, const float* __restrict__ b1,
    const float* __restrict__ g2, const float* __restrict__ b2,
    const float* __restrict__ bq, const float* __restrict__ bk,
    const float* __restrict__ bv,
    const float* __restrict__ b1f, const float* __restrict__ b2f,
    const float* __restrict__ lg, const float* __restrict__ lb,
    float* __restrict__ Q, float* __restrict__ xr, float* __restrict__ logtw,
    unsigned short* __restrict__ bfg, unsigned short* __restrict__ wf,
    unsigned short* __restrict__ qA, unsigned short* __restrict__ kB,
    unsigned short* __restrict__ vB,
    unsigned* __restrict__ bar,
    float* __restrict__ lf, float* __restrict__ w0, float* __restrict__ w1){
  __shared__ __align__(16) unsigned char smem[34944];
  unsigned* cnt = bar;
  unsigned* gen = bar + 8;
  int tid = threadIdx.x;
  int bid = blockIdx.x;
  int lane = tid & 63, w = tid >> 6;
  int quad = lane >> 4;

  // ---------------- phase 0: weight swizzle (prep) ----------------
  for (int idx = bid * 256 + tid; idx < 196608; idx += NBLK * 256){
    if (idx < 32768){
      int jj   = idx & 7;
      int ln   = (idx >> 3) & 63;
      int k0   = (idx >> 9) & 3;
      int nt   = idx >> 11;
      int d    = k0 * 32 + (ln >> 4) * 8 + jj;
      int col  = (nt & 7) * 16 + (ln & 15);
      int blk  = nt >> 3;
      bfg[idx] = bfbits(Wt[blk * D * D + d * D + col]);
    } else {
      int i2 = idx - 32768;
      int jj = i2 & 7, ln = (i2 >> 3) & 63, k0 = (i2 >> 9) & 3, nt = (i2 >> 11) & 7;
      int mat = i2 >> 14;
      int blk = mat / 5, m5 = mat % 5;
      const float* W = (m5 == 0 ? Wq : m5 == 1 ? Wk : m5 == 2 ? Wv : m5 == 3 ? W1 : W2)
                       + blk * D * D;
      int d = k0 * 32 + (ln >> 4) * 8 + jj;
      int col = nt * 16 + (ln & 15);
      wf[i2] = bfbits(W[d * D + col]);
    }
  }
  gridbar(cnt, gen);

  // ---------------- phase 1: causal timebias + LN1/QKV block0 ----------------
  {
    unsigned short* bsh = (unsigned short*)smem;          // 32 KB
    float* bts  = (float*)(smem + 32768);
    float* wtps = bts + 128;
    const bf16x8* bls = (const bf16x8*)bsh;
    int m = lane & 15;
    int niter = (bid < 64) ? 2 : 1;
    for (int it = 0; it < niter; ++it){
      int strip = it * 2048 + bid * 4 + w;                // 0..2303
      int b = 0;
#pragma unroll
      for (int i = 1; i < 8; ++i) if (strip >= 32 * i * (i + 1)) b = i;
      int r0 = strip - 32 * b * (b + 1);
      int q  = b * 64 + r0 / (b + 1);
      int kb = (r0 % (b + 1)) * 64;
      int wbase = q * L + kb;

      bf16x8 afr[4][4];
#pragma unroll
      for (int mt = 0; mt < 4; ++mt){
        const float* tp = T + (size_t)(wbase + mt * 16 + m) * D + quad * 8;
#pragma unroll
        for (int k0 = 0; k0 < 4; ++k0){
          float4 f0 = *(const float4*)(tp + k0 * 32);
          float4 f1 = *(const float4*)(tp + k0 * 32 + 4);
          afr[mt][k0] = cvt8(f0, f1);
        }
      }

#pragma unroll
      for (int blk = 0; blk < 2; ++blk){
        if (blk || it) __syncthreads();
        {
          const uint4* g = (const uint4*)(bfg + blk * 16384);
          uint4* s = (uint4*)bsh;
#pragma unroll
          for (int i = 0; i < 8; ++i) s[tid + i * 256] = g[tid + i * 256];
          if (tid < 128){ bts[tid] = bt[blk * 128 + tid]; wtps[tid] = wtp[blk * 128 + tid]; }
        }
        __syncthreads();

        f32x4 rs[4] = {{0,0,0,0},{0,0,0,0},{0,0,0,0},{0,0,0,0}};
#pragma unroll
        for (int ntl = 0; ntl < 8; ++ntl){
          f32x4 acc[4] = {{0,0,0,0},{0,0,0,0},{0,0,0,0},{0,0,0,0}};
#pragma unroll
          for (int k0 = 0; k0 < 4; ++k0){
            bf16x8 bfr = bls[(ntl * 4 + k0) * 64 + lane];
#pragma unroll
            for (int mt = 0; mt < 4; ++mt)
              acc[mt] = __builtin_amdgcn_mfma_f32_16x16x32_bf16(afr[mt][k0], bfr, acc[mt], 0, 0, 0);
          }
          float btv = bts[ntl * 16 + m];
          float wtv = wtps[ntl * 16 + m];
#pragma unroll
          for (int mt = 0; mt < 4; ++mt)
#pragma unroll
            for (int r = 0; r < 4; ++r)
              rs[mt][r] += fmaxf(acc[mt][r] + btv, 0.f) * wtv;
        }
#pragma unroll
        for (int mt = 0; mt < 4; ++mt)
#pragma unroll
          for (int r = 0; r < 4; ++r){
            float v = rs[mt][r];
            v += __shfl_xor(v, 1); v += __shfl_xor(v, 2);
            v += __shfl_xor(v, 4); v += __shfl_xor(v, 8);
            rs[mt][r] = v;
          }
        if (m == 0){
          float bp = btp[blk];
          float* out = logtw + blk * (L * L);
#pragma unroll
          for (int mt = 0; mt < 4; ++mt){
            float4 o;
            float s0 = rs[mt][0] + bp; o.x = -__logf(1.f + __expf(-s0));
            float s1 = rs[mt][1] + bp; o.y = -__logf(1.f + __expf(-s1));
            float s2 = rs[mt][2] + bp; o.z = -__logf(1.f + __expf(-s2));
            float s3 = rs[mt][3] + bp; o.w = -__logf(1.f + __expf(-s3));
            *(float4*)(out + wbase + mt * 16 + quad * 4) = o;
          }
        }
      }
    }
    if (bid >= 416)
      qkv_part(bid - 416, seqs, ls, g1, b1, wf, bq, bk, bv, Q, qA, kB, vB, smem);
  }
  gridbar(cnt, gen);

  // ---------------- phase 2: attention block 0 ----------------
  if (bid < 128)
    attn_part(bid, qA, kB, vB, logtw, ls, Q, w0, xr, smem);
  gridbar(cnt, gen);

  // ---------------- phase 3: FFN block 0 + LN1/QKV block 1 ----------------
  if (bid < 32)
    ffn_part(bid, xr, ls, g2, b2, wf, 3, b1f, b2f,
             1, g1 + D, b1 + D, 5, bq + D, bk + D, bv + D,
             Q, qA, kB, vB, 0, lg, lb, lf, smem);
  gridbar(cnt, gen);

  // ---------------- phase 4: attention block 1 ----------------
  if (bid < 128)
    attn_part(bid, qA, kB, vB, logtw + L * L, ls, Q, w1, xr, smem);
  gridbar(cnt, gen);

  // ---------------- phase 5: FFN block 1 + final LN ----------------
  if (bid < 32)
    ffn_part(bid, xr, ls, g2 + D, b2 + D, wf, 8, b1f + D, b2f + D,
             0, g1, b1, 0, bq, bk, bv,
             Q, qA, kB, vB, 1, lg, lb, lf, smem);
}

extern "C" void kernel_launch(void* const* d_in, const int* in_sizes, int n_in,
                              void* d_out, int out_size, void* d_ws, size_t ws_size,
                              hipStream_t stream){
  const int*   ls   = (const int*)d_in[0];
  const float* seqs = (const float*)d_in[1];
  const float* T    = (const float*)d_in[2];
  const float* Wq   = (const float*)d_in[3];
  const float* bq   = (const float*)d_in[4];
  const float* Wk   = (const float*)d_in[5];
  const float* bk   = (const float*)d_in[6];
  const float* Wv   = (const float*)d_in[7];
  const float* bv   = (const float*)d_in[8];
  const float* Wt   = (const float*)d_in[9];
  const float* bt   = (const float*)d_in[10];
  const float* Wtp  = (const float*)d_in[11];
  const float* btp  = (const float*)d_in[12];
  const float* g1   = (const float*)d_in[13];
  const float* b1   = (const float*)d_in[14];
  const float* g2   = (const float*)d_in[15];
  const float* b2   = (const float*)d_in[16];
  const float* W1   = (const float*)d_in[17];
  const float* b1f  = (const float*)d_in[18];
  const float* W2   = (const float*)d_in[19];
  const float* b2f  = (const float*)d_in[20];
  const float* lg   = (const float*)d_in[21];
  const float* lb   = (const float*)d_in[22];

  float* ws    = (float*)d_ws;
  float* Q     = ws;                  // 65536
  float* xr    = Q + 65536;           // 65536
  float* logtw = xr + 65536;          // 524288
  unsigned short* bfg = (unsigned short*)(logtw + 524288);      // 32768 ush
  unsigned short* wf  = bfg + 32768;  // 163840 ush
  unsigned short* qA  = wf + 163840;  // 65536 ush
  unsigned short* kB  = qA + 65536;   // 65536 ush
  unsigned short* vB  = kB + 65536;   // 65536 ush
  unsigned* bar = (unsigned*)(vB + 65536);   // 16 uints (64 B)

  float* outF = (float*)d_out;
  float* lf = outF;
  float* w0 = outF + 65536;
  float* w1 = w0 + 1048576;

  hipMemsetAsync(bar, 0, 64, stream);   // barrier counters must start at 0
  k_mega<<<NBLK, 256, 0, stream>>>(T, ls, seqs, Wt, Wq, Wk, Wv, W1, W2,
                                   bt, Wtp, btp, g1, b1, g2, b2,
                                   bq, bk, bv, b1f, b2f, lg, lb,
                                   Q, xr, logtw, bfg, wf, qA, kB, vB,
                                   bar, lf, w0, w1);
}

// Round 8
// 266.665 us; speedup vs baseline: 3.8869x; 3.8869x over previous
//
#include <hip/hip_runtime.h>

#define L 512
#define D 128
#define H 4
#define HD 32
#define XLD 132   // padded LDS leading dim (floats) to break 16-way bank conflicts
#define NTB 576   // causal timebias blocks (2304 strips / 4 waves)

typedef __bf16 bf16x8 __attribute__((ext_vector_type(8)));
typedef float  f32x4  __attribute__((ext_vector_type(4)));

__device__ __forceinline__ unsigned short bfbits(float v){
  __bf16 h = (__bf16)v; unsigned short u; __builtin_memcpy(&u, &h, 2); return u;
}
__device__ __forceinline__ bf16x8 cvt8(float4 a0, float4 a1){
  bf16x8 r;
  r[0] = (__bf16)a0.x; r[1] = (__bf16)a0.y; r[2] = (__bf16)a0.z; r[3] = (__bf16)a0.w;
  r[4] = (__bf16)a1.x; r[5] = (__bf16)a1.y; r[6] = (__bf16)a1.z; r[7] = (__bf16)a1.w;
  return r;
}

// -------- fragment-write helpers (thread owns value at (row, c)) ------------
__device__ __forceinline__ void write_qA(unsigned short* qA, int row, int c, float v){
  int qt = row >> 4, m = row & 15;
  int h = c >> 5, cc = c & 31;
  qA[(((qt * 4 + h) * 64) + (cc >> 3) * 16 + m) * 8 + (cc & 7)] = bfbits(v);
}
__device__ __forceinline__ void write_kB(unsigned short* kB, int row, int c, float v){
  int h = c >> 5, cc = c & 31;
  int nt = row >> 4;
  kB[((h * 32 + nt) * 64 + (cc >> 3) * 16 + (row & 15)) * 8 + (cc & 7)] = bfbits(v);
}
__device__ __forceinline__ void write_vB(unsigned short* vB, int row, int c, float v){
  int h = c >> 5, cc = c & 31;
  int kk = row >> 5, qv = (row >> 3) & 3, jv = row & 7;
  int nt = cc >> 4;
  vB[(((h * 16 + kk) * 2 + nt) * 64 + qv * 16 + (cc & 15)) * 8 + jv] = bfbits(v);
}

// ---- per-16-row stats (block of 256 threads; thread t: row=t>>4, seg=t&15) --
__device__ __forceinline__ void row_stats16(const float (*buf)[XLD], int tid,
                                            float* mean_s, float* rstd_s){
  int row_l = tid >> 4, seg = tid & 15;
  const float* p = &buf[row_l][seg * 8];
  float4 f0 = *(const float4*)p, f1 = *(const float4*)(p + 4);
  float sum = f0.x + f0.y + f0.z + f0.w + f1.x + f1.y + f1.z + f1.w;
  float sq  = f0.x*f0.x + f0.y*f0.y + f0.z*f0.z + f0.w*f0.w
            + f1.x*f1.x + f1.y*f1.y + f1.z*f1.z + f1.w*f1.w;
#pragma unroll
  for (int o = 1; o < 16; o <<= 1){ sum += __shfl_xor(sum, o); sq += __shfl_xor(sq, o); }
  if (seg == 0){
    float mn = sum * (1.f / 128.f);
    mean_s[row_l] = mn;
    rstd_s[row_l] = rsqrtf(fmaxf(sq * (1.f / 128.f) - mn * mn, 0.f) + 1e-8f);
  }
}

// ---- A-fragment builders from a 16x128 LDS tile ----------------------------
__device__ __forceinline__ void build_afr(const float (*buf)[XLD], int lane, bf16x8* afr){
  int m = lane & 15, quad = lane >> 4;
#pragma unroll
  for (int k0 = 0; k0 < 4; ++k0){
    const float* p = &buf[m][k0 * 32 + quad * 8];
    afr[k0] = cvt8(*(const float4*)p, *(const float4*)(p + 4));
  }
}
__device__ __forceinline__ void build_afr_ln(const float (*buf)[XLD], int lane,
    const float* mean_s, const float* rstd_s,
    const float* __restrict__ g, const float* __restrict__ b, bf16x8* afr){
  int m = lane & 15, quad = lane >> 4;
  float mn = mean_s[m], rs = rstd_s[m];
#pragma unroll
  for (int k0 = 0; k0 < 4; ++k0){
    int c0 = k0 * 32 + quad * 8;
    const float* p = &buf[m][c0];
    float4 a0 = *(const float4*)p, a1 = *(const float4*)(p + 4);
    float q[8];
    q[0]=(a0.x-mn)*rs*g[c0+0]+b[c0+0]; q[1]=(a0.y-mn)*rs*g[c0+1]+b[c0+1];
    q[2]=(a0.z-mn)*rs*g[c0+2]+b[c0+2]; q[3]=(a0.w-mn)*rs*g[c0+3]+b[c0+3];
    q[4]=(a1.x-mn)*rs*g[c0+4]+b[c0+4]; q[5]=(a1.y-mn)*rs*g[c0+5]+b[c0+5];
    q[6]=(a1.z-mn)*rs*g[c0+6]+b[c0+6]; q[7]=(a1.w-mn)*rs*g[c0+7]+b[c0+7];
    bf16x8 r;
    r[0]=(__bf16)q[0]; r[1]=(__bf16)q[1]; r[2]=(__bf16)q[2]; r[3]=(__bf16)q[3];
    r[4]=(__bf16)q[4]; r[5]=(__bf16)q[5]; r[6]=(__bf16)q[6]; r[7]=(__bf16)q[7];
    afr[k0] = r;
  }
}

// ------------- prep: swizzle Wt (timebias layout) + 10 GEMM weights ---------
// wf layout (bf16x8 units): [((mat*8 + nt)*4 + k0)*64 + lane], mat = blk*5 + {q,k,v,W1,W2}
__global__ void k_prep(const float* __restrict__ Wt,
                       const float* __restrict__ Wq, const float* __restrict__ Wk,
                       const float* __restrict__ Wv, const float* __restrict__ W1,
                       const float* __restrict__ W2,
                       unsigned short* __restrict__ bfg, unsigned short* __restrict__ wf){
  int idx = blockIdx.x * 256 + threadIdx.x;      // 196608 threads
  if (idx < 32768){
    int jj   = idx & 7;
    int lane = (idx >> 3) & 63;
    int k0   = (idx >> 9) & 3;
    int nt   = idx >> 11;
    int d    = k0 * 32 + (lane >> 4) * 8 + jj;
    int col  = (nt & 7) * 16 + (lane & 15);
    int blk  = nt >> 3;
    bfg[idx] = bfbits(Wt[blk * D * D + d * D + col]);
  } else {
    int i2 = idx - 32768;
    int jj = i2 & 7, lane = (i2 >> 3) & 63, k0 = (i2 >> 9) & 3, nt = (i2 >> 11) & 7;
    int mat = i2 >> 14;                          // 0..9
    int blk = mat / 5, m5 = mat % 5;
    const float* W = (m5 == 0 ? Wq : m5 == 1 ? Wk : m5 == 2 ? Wv : m5 == 3 ? W1 : W2)
                     + blk * D * D;
    int d = k0 * 32 + (lane >> 4) * 8 + jj;
    int col = nt * 16 + (lane & 15);
    wf[i2] = bfbits(W[d * D + col]);
  }
}

// ----- fused launch: causal timebias (blocks < NTB) + LN1/QKV block0 --------
// timebias: only (q,k) rows with k <= q are computed (causal mask kills k > q;
// pad-row weights are uniform and independent of logtw).
__global__ __launch_bounds__(256, 2) void k_tb_qkv(
    const float* __restrict__ T, const unsigned short* __restrict__ bfg,
    const float* __restrict__ bt, const float* __restrict__ wtp,
    const float* __restrict__ btp, float* __restrict__ logtw,
    const float* __restrict__ src, const int* __restrict__ ls,
    const float* __restrict__ g1, const float* __restrict__ b1,
    const unsigned short* __restrict__ wf,
    const float* __restrict__ bq, const float* __restrict__ bk,
    const float* __restrict__ bv,
    float* __restrict__ Q, unsigned short* __restrict__ qA,
    unsigned short* __restrict__ kB, unsigned short* __restrict__ vB){
  __shared__ __align__(16) unsigned short bsh[16384];   // 32 KB (timebias)
  __shared__ float bts[128], wtps[128];
  __shared__ float xs[16][XLD];                         // (qkv)
  __shared__ float mean_s[16], rstd_s[16];
  __shared__ float g1s[128], b1s[128];
  int tid = threadIdx.x;
  int lane = tid & 63, w = tid >> 6;
  int quad = lane >> 4;

  if (blockIdx.x < NTB){
    // ---------------- causal timebias ----------------
    int m = lane & 15;
    const bf16x8* bls = (const bf16x8*)bsh;
    // strip id -> (q, k_base): bands b=q>>6 have (b+1) strips per q
    int strip = blockIdx.x * 4 + w;              // 0..2303
    int b = 0;
#pragma unroll
    for (int i = 1; i < 8; ++i) if (strip >= 32 * i * (i + 1)) b = i;
    int r0 = strip - 32 * b * (b + 1);
    int q  = b * 64 + r0 / (b + 1);
    int kb = (r0 % (b + 1)) * 64;
    int wbase = q * L + kb;                      // flat row into T / logtw[blk]

    bf16x8 afr[4][4];
#pragma unroll
    for (int mt = 0; mt < 4; ++mt){
      const float* tp = T + (size_t)(wbase + mt * 16 + m) * D + quad * 8;
#pragma unroll
      for (int k0 = 0; k0 < 4; ++k0){
        float4 f0 = *(const float4*)(tp + k0 * 32);
        float4 f1 = *(const float4*)(tp + k0 * 32 + 4);
        afr[mt][k0] = cvt8(f0, f1);
      }
    }

#pragma unroll
    for (int blk = 0; blk < 2; ++blk){
      if (blk) __syncthreads();                 // protect bsh overwrite
      {
        const uint4* g = (const uint4*)(bfg + blk * 16384);
        uint4* s = (uint4*)bsh;
#pragma unroll
        for (int i = 0; i < 8; ++i) s[tid + i * 256] = g[tid + i * 256];
        if (tid < 128){ bts[tid] = bt[blk * 128 + tid]; wtps[tid] = wtp[blk * 128 + tid]; }
      }
      __syncthreads();

      f32x4 rs[4] = {{0,0,0,0},{0,0,0,0},{0,0,0,0},{0,0,0,0}};
#pragma unroll
      for (int ntl = 0; ntl < 8; ++ntl){
        f32x4 acc[4] = {{0,0,0,0},{0,0,0,0},{0,0,0,0},{0,0,0,0}};
#pragma unroll
        for (int k0 = 0; k0 < 4; ++k0){
          bf16x8 bfr = bls[(ntl * 4 + k0) * 64 + lane];
#pragma unroll
          for (int mt = 0; mt < 4; ++mt)
            acc[mt] = __builtin_amdgcn_mfma_f32_16x16x32_bf16(afr[mt][k0], bfr, acc[mt], 0, 0, 0);
        }
        float btv = bts[ntl * 16 + m];
        float wtv = wtps[ntl * 16 + m];
#pragma unroll
        for (int mt = 0; mt < 4; ++mt)
#pragma unroll
          for (int r = 0; r < 4; ++r)
            rs[mt][r] += fmaxf(acc[mt][r] + btv, 0.f) * wtv;
      }
#pragma unroll
      for (int mt = 0; mt < 4; ++mt)
#pragma unroll
        for (int r = 0; r < 4; ++r){
          float v = rs[mt][r];
          v += __shfl_xor(v, 1); v += __shfl_xor(v, 2);
          v += __shfl_xor(v, 4); v += __shfl_xor(v, 8);
          rs[mt][r] = v;
        }
      if (m == 0){
        float bp = btp[blk];
        float* out = logtw + blk * (L * L);
#pragma unroll
        for (int mt = 0; mt < 4; ++mt){
          float4 o;
          float s0 = rs[mt][0] + bp; o.x = -__logf(1.f + __expf(-s0));
          float s1 = rs[mt][1] + bp; o.y = -__logf(1.f + __expf(-s1));
          float s2 = rs[mt][2] + bp; o.z = -__logf(1.f + __expf(-s2));
          float s3 = rs[mt][3] + bp; o.w = -__logf(1.f + __expf(-s3));
          *(float4*)(out + wbase + mt * 16 + quad * 4) = o;
        }
      }
    }
    return;
  }

  // ---------------- LN1 + QKV for transformer block 0 ----------------
  int bi = blockIdx.x - NTB;                     // 0..95
  int rowbase = (bi & 31) * 16;
  int mat = bi >> 5;                             // 0=q,1=k,2=v
  int row_l = tid >> 4, seg = tid & 15;

  const float* sp = src + (rowbase + row_l) * D + seg * 8;
  float4 f0 = *(const float4*)sp, f1 = *(const float4*)(sp + 4);
  if (ls[rowbase + row_l] == 0){
    f0 = make_float4(0,0,0,0); f1 = make_float4(0,0,0,0);
  }
  *(float4*)&xs[row_l][seg * 8] = f0;
  *(float4*)&xs[row_l][seg * 8 + 4] = f1;
  if (mat == 0 && tid < 128){ g1s[tid] = g1[tid]; b1s[tid] = b1[tid]; }
  __syncthreads();
  if (mat == 0){
    row_stats16(xs, tid, mean_s, rstd_s);
    __syncthreads();
    float mn = mean_s[row_l], rs = rstd_s[row_l];
    float* qp = Q + (rowbase + row_l) * D + seg * 8;
    float4 o0, o1;
    int c0 = seg * 8;
    o0.x=(f0.x-mn)*rs*g1s[c0+0]+b1s[c0+0]; o0.y=(f0.y-mn)*rs*g1s[c0+1]+b1s[c0+1];
    o0.z=(f0.z-mn)*rs*g1s[c0+2]+b1s[c0+2]; o0.w=(f0.w-mn)*rs*g1s[c0+3]+b1s[c0+3];
    o1.x=(f1.x-mn)*rs*g1s[c0+4]+b1s[c0+4]; o1.y=(f1.y-mn)*rs*g1s[c0+5]+b1s[c0+5];
    o1.z=(f1.z-mn)*rs*g1s[c0+6]+b1s[c0+6]; o1.w=(f1.w-mn)*rs*g1s[c0+7]+b1s[c0+7];
    *(float4*)qp = o0; *(float4*)(qp + 4) = o1;
  }

  int mcol = lane & 15;
  bf16x8 afr[4];
  if (mat == 0) build_afr_ln(xs, lane, mean_s, rstd_s, g1s, b1s, afr);
  else          build_afr(xs, lane, afr);

  const float* bias_v = (mat == 0 ? bq : mat == 1 ? bk : bv);
#pragma unroll
  for (int jl = 0; jl < 2; ++jl){
    int nt = w * 2 + jl;
    const bf16x8* wfb = (const bf16x8*)wf + ((size_t)mat * 8 + nt) * 4 * 64;
    f32x4 acc = {0, 0, 0, 0};
#pragma unroll
    for (int k0 = 0; k0 < 4; ++k0)
      acc = __builtin_amdgcn_mfma_f32_16x16x32_bf16(afr[k0], wfb[k0 * 64 + lane], acc, 0, 0, 0);
    int c = nt * 16 + mcol;
    float bias = bias_v[c];
#pragma unroll
    for (int r = 0; r < 4; ++r){
      int row = rowbase + quad * 4 + r;
      float v = acc[r] + bias;
      if (mat == 0) write_qA(qA, row, c, v);
      else if (mat == 1) write_kB(kB, row, c, v);
      else write_vB(vB, row, c, v);
    }
  }
}

// ---------------- MFMA attention: block = (qtile of 16 rows, head) ----------
// Causal skip: wave chunks entirely above the diagonal skip score/PV MFMAs.
__global__ __launch_bounds__(256) void k_attn(
    const unsigned short* __restrict__ qA, const unsigned short* __restrict__ kB,
    const unsigned short* __restrict__ vB, const float* __restrict__ logtw,
    const int* __restrict__ ls, const float* __restrict__ Q,
    float* __restrict__ wout, float* __restrict__ xr){
  __shared__ __align__(16) unsigned short pa[16 * 64 * 8];
  __shared__ float pvp[4][2][64][4];
  __shared__ float smax[4][16], ssum[4][16];
  int qt = blockIdx.x >> 2, h = blockIdx.x & 3;
  int tid = threadIdx.x, lane = tid & 63, w = tid >> 6;
  int quad = lane >> 4, mcol = lane & 15;
  const float RS = 0.17677669529663687f;
  int row_max = qt * 16 + 15;
  bool skipw = (w * 128) > row_max;              // whole 128-col chunk masked

  float e[8][4];
  if (!skipw){
    bf16x8 qf = ((const bf16x8*)qA)[(qt * 4 + h) * 64 + lane];
    f32x4 acc[8];
#pragma unroll
    for (int nt8 = 0; nt8 < 8; ++nt8){
      bf16x8 bf = ((const bf16x8*)kB)[(h * 32 + w * 8 + nt8) * 64 + lane];
      f32x4 z = {0, 0, 0, 0};
      acc[nt8] = __builtin_amdgcn_mfma_f32_16x16x32_bf16(qf, bf, z, 0, 0, 0);
    }
#pragma unroll
    for (int nt8 = 0; nt8 < 8; ++nt8){
      int col = w * 128 + nt8 * 16 + mcol;
#pragma unroll
      for (int r = 0; r < 4; ++r){
        int row = qt * 16 + quad * 4 + r;
        float sv = (acc[nt8][r] + logtw[row * L + col]) * RS;
        e[nt8][r] = (col <= row) ? sv : -3e38f;
      }
    }
  } else {
#pragma unroll
    for (int nt8 = 0; nt8 < 8; ++nt8)
#pragma unroll
      for (int r = 0; r < 4; ++r) e[nt8][r] = -3e38f;
  }

  float mx4[4] = {-3e38f, -3e38f, -3e38f, -3e38f};
#pragma unroll
  for (int nt8 = 0; nt8 < 8; ++nt8)
#pragma unroll
    for (int r = 0; r < 4; ++r) mx4[r] = fmaxf(mx4[r], e[nt8][r]);
#pragma unroll
  for (int r = 0; r < 4; ++r){
    float v = mx4[r];
    v = fmaxf(v, __shfl_xor(v, 1)); v = fmaxf(v, __shfl_xor(v, 2));
    v = fmaxf(v, __shfl_xor(v, 4)); v = fmaxf(v, __shfl_xor(v, 8));
    mx4[r] = v;
  }
  if (mcol == 0){
#pragma unroll
    for (int r = 0; r < 4; ++r) smax[w][quad * 4 + r] = mx4[r];
  }
  __syncthreads();
  float mxr[4], sum4[4] = {0, 0, 0, 0};
#pragma unroll
  for (int r = 0; r < 4; ++r){
    int rr = quad * 4 + r;
    mxr[r] = fmaxf(fmaxf(smax[0][rr], smax[1][rr]), fmaxf(smax[2][rr], smax[3][rr]));
  }
#pragma unroll
  for (int nt8 = 0; nt8 < 8; ++nt8)
#pragma unroll
    for (int r = 0; r < 4; ++r){
      float sv = e[nt8][r];
      float ev = (sv > -1e38f) ? __expf(sv - mxr[r]) : 0.f;
      e[nt8][r] = ev;
      sum4[r] += ev;
    }
#pragma unroll
  for (int r = 0; r < 4; ++r){
    float v = sum4[r];
    v += __shfl_xor(v, 1); v += __shfl_xor(v, 2);
    v += __shfl_xor(v, 4); v += __shfl_xor(v, 8);
    sum4[r] = v;
  }
  if (mcol == 0){
#pragma unroll
    for (int r = 0; r < 4; ++r) ssum[w][quad * 4 + r] = sum4[r];
  }
  __syncthreads();
  float inv[4]; int padr[4];
#pragma unroll
  for (int r = 0; r < 4; ++r){
    int rr = quad * 4 + r;
    inv[r] = 1.f / (ssum[0][rr] + ssum[1][rr] + ssum[2][rr] + ssum[3][rr]);
    padr[r] = (ls[qt * 16 + rr] == 0);
  }
#pragma unroll
  for (int nt8 = 0; nt8 < 8; ++nt8){
    int col = w * 128 + nt8 * 16 + mcol;
    int kk = col >> 5, qk = (col >> 3) & 3, jj = col & 7;
#pragma unroll
    for (int r = 0; r < 4; ++r){
      int rl = quad * 4 + r;
      float wv = padr[r] ? (1.f / 512.f) : e[nt8][r] * inv[r];
      wout[h * (L * L) + (qt * 16 + rl) * L + col] = wv;
      if (!skipw) pa[(kk * 64 + qk * 16 + rl) * 8 + jj] = bfbits(wv);
    }
  }

  f32x4 pacc[2] = {{0,0,0,0},{0,0,0,0}};
  if (!skipw){
#pragma unroll
    for (int kk4 = 0; kk4 < 4; ++kk4){
      int kk = w * 4 + kk4;
      bf16x8 af = ((const bf16x8*)pa)[kk * 64 + lane];
#pragma unroll
      for (int nt = 0; nt < 2; ++nt){
        bf16x8 bf = ((const bf16x8*)vB)[((h * 16 + kk) * 2 + nt) * 64 + lane];
        pacc[nt] = __builtin_amdgcn_mfma_f32_16x16x32_bf16(af, bf, pacc[nt], 0, 0, 0);
      }
    }
  }
#pragma unroll
  for (int nt = 0; nt < 2; ++nt)
#pragma unroll
    for (int r = 0; r < 4; ++r) pvp[w][nt][lane][r] = pacc[nt][r];
  __syncthreads();
  if (w < 2){
    int nt = w;
#pragma unroll
    for (int r = 0; r < 4; ++r){
      float o = pvp[0][nt][lane][r] + pvp[1][nt][lane][r]
              + pvp[2][nt][lane][r] + pvp[3][nt][lane][r];
      int row = qt * 16 + quad * 4 + r;
      int cg = h * HD + nt * 16 + mcol;
      xr[row * D + cg] = Q[row * D + cg] + o;
    }
  }
}

// ---- MFMA LN2+FFN (+keep); optional fused LN1+QKV of next block / final LN --
__global__ __launch_bounds__(256) void k_ffn_m(
    const float* __restrict__ xr, const int* __restrict__ ls,
    const float* __restrict__ g2, const float* __restrict__ b2,
    const unsigned short* __restrict__ wf, int mat1,
    const float* __restrict__ b1f, const float* __restrict__ b2f,
    int fuse_qkv, const float* __restrict__ g1, const float* __restrict__ b1,
    int matq, const float* __restrict__ bq, const float* __restrict__ bk,
    const float* __restrict__ bv,
    float* __restrict__ Q, unsigned short* __restrict__ qA,
    unsigned short* __restrict__ kB, unsigned short* __restrict__ vB,
    int fuse_lnf, const float* __restrict__ lg, const float* __restrict__ lb,
    float* __restrict__ lf){
  __shared__ float xs[16][XLD];
  __shared__ float x2s[16][XLD];
  __shared__ float y1s[16][XLD];
  __shared__ float xos[16][XLD];
  __shared__ float mean_s[16], rstd_s[16];
  __shared__ float gs[128], bs[128];
  int tid = threadIdx.x, rowbase = blockIdx.x * 16;
  int row_l = tid >> 4, seg = tid & 15;
  int lane = tid & 63, w = tid >> 6;
  int quad = lane >> 4, mcol = lane & 15;

  {
    const float* sp = xr + (rowbase + row_l) * D + seg * 8;
    *(float4*)&xs[row_l][seg * 8] = *(const float4*)sp;
    *(float4*)&xs[row_l][seg * 8 + 4] = *(const float4*)(sp + 4);
    if (tid < 128){ gs[tid] = g2[tid]; bs[tid] = b2[tid]; }
  }
  __syncthreads();
  row_stats16(xs, tid, mean_s, rstd_s);
  __syncthreads();
  {
    float mn = mean_s[row_l], rs = rstd_s[row_l];
#pragma unroll
    for (int i = 0; i < 8; ++i){
      int c = seg * 8 + i;
      x2s[row_l][c] = (xs[row_l][c] - mn) * rs * gs[c] + bs[c];
    }
  }
  __syncthreads();

  bf16x8 afr[4];
  build_afr(x2s, lane, afr);
#pragma unroll
  for (int jl = 0; jl < 2; ++jl){
    int nt = w * 2 + jl;
    const bf16x8* wfb = (const bf16x8*)wf + ((size_t)mat1 * 8 + nt) * 4 * 64;
    f32x4 acc = {0, 0, 0, 0};
#pragma unroll
    for (int k0 = 0; k0 < 4; ++k0)
      acc = __builtin_amdgcn_mfma_f32_16x16x32_bf16(afr[k0], wfb[k0 * 64 + lane], acc, 0, 0, 0);
    int c = nt * 16 + mcol;
    float bias = b1f[c];
#pragma unroll
    for (int r = 0; r < 4; ++r)
      y1s[quad * 4 + r][c] = fmaxf(acc[r] + bias, 0.f);
  }
  __syncthreads();

  build_afr(y1s, lane, afr);
#pragma unroll
  for (int jl = 0; jl < 2; ++jl){
    int nt = w * 2 + jl;
    const bf16x8* wfb = (const bf16x8*)wf + ((size_t)(mat1 + 1) * 8 + nt) * 4 * 64;
    f32x4 acc = {0, 0, 0, 0};
#pragma unroll
    for (int k0 = 0; k0 < 4; ++k0)
      acc = __builtin_amdgcn_mfma_f32_16x16x32_bf16(afr[k0], wfb[k0 * 64 + lane], acc, 0, 0, 0);
    int c = nt * 16 + mcol;
    float bias = b2f[c];
#pragma unroll
    for (int r = 0; r < 4; ++r){
      int rl = quad * 4 + r;
      float kp = (ls[rowbase + rl] != 0) ? 1.f : 0.f;
      xos[rl][c] = (x2s[rl][c] + acc[r] + bias) * kp;   // residual adds post-LN2 x2
    }
  }
  __syncthreads();

  if (fuse_qkv){
    if (tid < 128){ gs[tid] = g1[tid]; bs[tid] = b1[tid]; }
    row_stats16(xos, tid, mean_s, rstd_s);
    __syncthreads();
    {
      float mn = mean_s[row_l], rs = rstd_s[row_l];
      float* qp = Q + (rowbase + row_l) * D + seg * 8;
      float4 o0, o1;
      int c0 = seg * 8;
      o0.x=(xos[row_l][c0+0]-mn)*rs*gs[c0+0]+bs[c0+0];
      o0.y=(xos[row_l][c0+1]-mn)*rs*gs[c0+1]+bs[c0+1];
      o0.z=(xos[row_l][c0+2]-mn)*rs*gs[c0+2]+bs[c0+2];
      o0.w=(xos[row_l][c0+3]-mn)*rs*gs[c0+3]+bs[c0+3];
      o1.x=(xos[row_l][c0+4]-mn)*rs*gs[c0+4]+bs[c0+4];
      o1.y=(xos[row_l][c0+5]-mn)*rs*gs[c0+5]+bs[c0+5];
      o1.z=(xos[row_l][c0+6]-mn)*rs*gs[c0+6]+bs[c0+6];
      o1.w=(xos[row_l][c0+7]-mn)*rs*gs[c0+7]+bs[c0+7];
      *(float4*)qp = o0; *(float4*)(qp + 4) = o1;
    }
    bf16x8 afrQ[4], afrX[4];
    build_afr_ln(xos, lane, mean_s, rstd_s, gs, bs, afrQ);
    build_afr(xos, lane, afrX);
#pragma unroll
    for (int jl = 0; jl < 6; ++jl){
      int j = w * 6 + jl;
      int mat = j >> 3, nt = j & 7;
      const bf16x8* wfb = (const bf16x8*)wf + ((size_t)(matq + mat) * 8 + nt) * 4 * 64;
      f32x4 acc = {0, 0, 0, 0};
#pragma unroll
      for (int k0 = 0; k0 < 4; ++k0)
        acc = __builtin_amdgcn_mfma_f32_16x16x32_bf16(mat == 0 ? afrQ[k0] : afrX[k0],
                                                      wfb[k0 * 64 + lane], acc, 0, 0, 0);
      int c = nt * 16 + mcol;
      float bias = (mat == 0 ? bq : mat == 1 ? bk : bv)[c];
#pragma unroll
      for (int r = 0; r < 4; ++r){
        int row = rowbase + quad * 4 + r;
        float v = acc[r] + bias;
        if (mat == 0) write_qA(qA, row, c, v);
        else if (mat == 1) write_kB(kB, row, c, v);
        else write_vB(vB, row, c, v);
      }
    }
  }

  if (fuse_lnf){
    if (tid < 128){ gs[tid] = lg[tid]; bs[tid] = lb[tid]; }
    row_stats16(xos, tid, mean_s, rstd_s);
    __syncthreads();
    float mn = mean_s[row_l], rs = rstd_s[row_l];
    float* op = lf + (rowbase + row_l) * D + seg * 8;
    float4 o0, o1;
    int c0 = seg * 8;
    o0.x=(xos[row_l][c0+0]-mn)*rs*gs[c0+0]+bs[c0+0];
    o0.y=(xos[row_l][c0+1]-mn)*rs*gs[c0+1]+bs[c0+1];
    o0.z=(xos[row_l][c0+2]-mn)*rs*gs[c0+2]+bs[c0+2];
    o0.w=(xos[row_l][c0+3]-mn)*rs*gs[c0+3]+bs[c0+3];
    o1.x=(xos[row_l][c0+4]-mn)*rs*gs[c0+4]+bs[c0+4];
    o1.y=(xos[row_l][c0+5]-mn)*rs*gs[c0+5]+bs[c0+5];
    o1.z=(xos[row_l][c0+6]-mn)*rs*gs[c0+6]+bs[c0+6];
    o1.w=(xos[row_l][c0+7]-mn)*rs*gs[c0+7]+bs[c0+7];
    *(float4*)op = o0; *(float4*)(op + 4) = o1;
  }
}

extern "C" void kernel_launch(void* const* d_in, const int* in_sizes, int n_in,
                              void* d_out, int out_size, void* d_ws, size_t ws_size,
                              hipStream_t stream){
  const int*   ls   = (const int*)d_in[0];
  const float* seqs = (const float*)d_in[1];
  const float* T    = (const float*)d_in[2];
  const float* Wq   = (const float*)d_in[3];
  const float* bq   = (const float*)d_in[4];
  const float* Wk   = (const float*)d_in[5];
  const float* bk   = (const float*)d_in[6];
  const float* Wv   = (const float*)d_in[7];
  const float* bv   = (const float*)d_in[8];
  const float* Wt   = (const float*)d_in[9];
  const float* bt   = (const float*)d_in[10];
  const float* Wtp  = (const float*)d_in[11];
  const float* btp  = (const float*)d_in[12];
  const float* g1   = (const float*)d_in[13];
  const float* b1   = (const float*)d_in[14];
  const float* g2   = (const float*)d_in[15];
  const float* b2   = (const float*)d_in[16];
  const float* W1   = (const float*)d_in[17];
  const float* b1f  = (const float*)d_in[18];
  const float* W2   = (const float*)d_in[19];
  const float* b2f  = (const float*)d_in[20];
  const float* lg   = (const float*)d_in[21];
  const float* lb   = (const float*)d_in[22];

  float* ws    = (float*)d_ws;
  float* Q     = ws;                  // 65536
  float* xr    = Q + 65536;           // 65536
  float* logtw = xr + 65536;          // 2*262144 (upper triangle left unwritten; never read)
  unsigned short* bfg = (unsigned short*)(logtw + 2 * 262144);  // 32768
  unsigned short* wf  = bfg + 32768;  // 163840
  unsigned short* qA  = wf + 163840;  // 65536
  unsigned short* kB  = qA + 65536;   // 65536
  unsigned short* vB  = kB + 65536;   // 65536

  float* outF = (float*)d_out;
  float* lf = outF;
  float* w0 = outF + 65536;
  float* w1 = w0 + 1048576;

  k_prep  <<<768, 256, 0, stream>>>(Wt, Wq, Wk, Wv, W1, W2, bfg, wf);
  // fused: causal timebias (576 blocks) + LN1/QKV block0 (96 blocks)
  k_tb_qkv<<<NTB + 96, 256, 0, stream>>>(T, bfg, bt, Wtp, btp, logtw,
                                         seqs, ls, g1, b1, wf, bq, bk, bv,
                                         Q, qA, kB, vB);
  // block 0
  k_attn<<<128, 256, 0, stream>>>(qA, kB, vB, logtw, ls, Q, w0, xr);
  k_ffn_m<<<32, 256, 0, stream>>>(xr, ls, g2, b2, wf, 3, b1f, b2f,
                                  1, g1 + D, b1 + D, 5, bq + D, bk + D, bv + D,
                                  Q, qA, kB, vB,
                                  0, lg, lb, lf);
  // block 1
  k_attn<<<128, 256, 0, stream>>>(qA, kB, vB, logtw + L * L, ls, Q, w1, xr);
  k_ffn_m<<<32, 256, 0, stream>>>(xr, ls, g2 + D, b2 + D, wf, 8, b1f + D, b2f + D,
                                  0, g1, b1, 0, bq, bk, bv,
                                  Q, qA, kB, vB,
                                  1, lg, lb, lf);
}